// Round 6
// baseline (244.625 us; speedup 1.0000x reference)
//
#include <hip/hip_runtime.h>
#include <hip/hip_bf16.h>
#include <math.h>

#define B_ 2
#define H_ 12
#define S_ 1024
#define D_ 128
#define TQ 64
#define TK 32
#define SCALE 0.08838834764831843f

#define QROWS (S_ + 16)            /* 1040 */
#define KROWS (16 + S_ + 16)       /* 1056 */

#define QBLK 3120                  /* 24*1040*128/4/256 */
#define KBLK 3168                  /* 24*1056*128/4/256 */
#define VBLK 3072                  /* 24*32*4 transpose tiles */

#define SCW 56                     /* sc row stride (shorts), 112 B = 16B-mult */

typedef __attribute__((ext_vector_type(8))) short short8;
typedef __attribute__((ext_vector_type(4))) float floatx4;

__device__ __forceinline__ unsigned short f2b(float f) {
    return __builtin_bit_cast(unsigned short, __float2bfloat16(f));
}

// ---- fused prepass: Q/K f32->bf16 padded, V -> V^T bf16 --------------------
__global__ __launch_bounds__(256) void prep_kernel(
    const float* __restrict__ Q, const float* __restrict__ K,
    const float* __restrict__ V,
    unsigned short* __restrict__ Qp, unsigned short* __restrict__ Kp,
    unsigned short* __restrict__ Vt)
{
    __shared__ float ls[32][33];
    const int bid = blockIdx.x;
    const int tid = threadIdx.x;
    if (bid < QBLK) {
        int e0 = (bid * 256 + tid) * 4;
        int bh = e0 / (QROWS * D_);
        int rem = e0 - bh * (QROWS * D_);
        int r = rem >> 7, d = rem & 127;
        int sr = r - 16;
        float4 v = make_float4(0.f, 0.f, 0.f, 0.f);
        if (sr >= 0 && sr < S_) v = *(const float4*)(Q + ((size_t)bh * S_ + sr) * D_ + d);
        ushort4 o; o.x = f2b(v.x); o.y = f2b(v.y); o.z = f2b(v.z); o.w = f2b(v.w);
        *(ushort4*)(Qp + ((size_t)bh * QROWS + r) * D_ + d) = o;
    } else if (bid < QBLK + KBLK) {
        int e0 = ((bid - QBLK) * 256 + tid) * 4;
        int bh = e0 / (KROWS * D_);
        int rem = e0 - bh * (KROWS * D_);
        int r = rem >> 7, d = rem & 127;
        int sr = r - 16;
        float4 v = make_float4(0.f, 0.f, 0.f, 0.f);
        if (sr >= 0 && sr < S_) v = *(const float4*)(K + ((size_t)bh * S_ + sr) * D_ + d);
        ushort4 o; o.x = f2b(v.x); o.y = f2b(v.y); o.z = f2b(v.z); o.w = f2b(v.w);
        *(ushort4*)(Kp + ((size_t)bh * KROWS + r) * D_ + d) = o;
    } else {
        int b = bid - (QBLK + KBLK);
        int dt = b & 3; int kt = (b >> 2) & 31; int bh = b >> 7;
        int lk = tid >> 3, ld = (tid & 7) * 4;
        float4 v = *(const float4*)(V + ((size_t)bh * S_ + kt * 32 + lk) * D_ + dt * 32 + ld);
        ls[lk][ld + 0] = v.x; ls[lk][ld + 1] = v.y; ls[lk][ld + 2] = v.z; ls[lk][ld + 3] = v.w;
        __syncthreads();
        int lk2 = tid >> 3, lc = (tid & 7) * 4;
        ushort4 o;
        o.x = f2b(ls[lc + 0][lk2]); o.y = f2b(ls[lc + 1][lk2]);
        o.z = f2b(ls[lc + 2][lk2]); o.w = f2b(ls[lc + 3][lk2]);
        *(ushort4*)(Vt + ((size_t)bh * D_ + dt * 32 + lk2) * S_ + kt * 32 + lc) = o;
    }
}

// ---- main fused kernel: QK, conv, PV all on MFMA ---------------------------
__global__ __launch_bounds__(256, 2) void conv_attn_mfma(
    const unsigned short* __restrict__ Qp,  // [24][1040][128] bf16
    const unsigned short* __restrict__ Kp,  // [24][1056][128] bf16
    const unsigned short* __restrict__ Vt,  // [24][128][1024] bf16
    const float* __restrict__ W,            // [12][6][11]
    float* __restrict__ O)                  // [24][1024][128] f32
{
    __shared__ __align__(16) unsigned short Qs[80][136];      // 21760 B
    __shared__ __align__(16) unsigned short sc[2][80][SCW];   // 17920 B (dbuf, bf16)
    __shared__ __align__(16) unsigned short Pst[4][16][40];   //  5120 B (per-wave)
    __shared__ float Wf[66];

    const int tid = threadIdx.x;
    const int wv = tid >> 6;
    const int ln = tid & 63;
    const int l15 = ln & 15;
    const int qd = ln >> 4;

    // bh swizzle: XCD x sees only 3 bh values (K/V set ~1.6MB < 4MiB L2).
    // qt order pairs heavy/light so co-resident + backfill blocks balance.
    const int bid = blockIdx.x;
    const int bh = (bid & 7) * 3 + ((bid >> 3) % 3);
    const int g = bid / 24;
    const int qt = (g & 1) ? (g >> 1) : (15 - (g >> 1));
    const int h = bh % H_;
    const int q0 = qt * TQ;

    const unsigned short* Qb = Qp + (size_t)bh * QROWS * D_;
    const unsigned short* Kb = Kp + (size_t)bh * KROWS * D_;
    const unsigned short* Vb = Vt + (size_t)bh * D_ * S_;

    if (tid < 66) Wf[tid] = W[h * 66 + tid];

    // stage Q rows q0-16 .. q0+63 (Qp row q0+r)
    for (int idx = tid; idx < 80 * 16; idx += 256) {
        int r = idx >> 4, c8 = (idx & 15) * 8;
        *(short8*)&Qs[r][c8] = *(const short8*)(Qb + (size_t)(q0 + r) * D_ + c8);
    }
    __syncthreads();

    // ---- build banded-Toeplitz conv B-fragments (once per block) -----------
    // B_i[c][t] = W[i][c-t-3] for 0<=c-t-3<=10 else 0;  lane holds B[qd*8+j][l15]
    short8 bfr[6];
    #pragma unroll
    for (int i = 0; i < 6; ++i) {
        short8 b;
        #pragma unroll
        for (int j = 0; j < 8; ++j) {
            int widx = qd * 8 + j - l15 - 3;
            float v = (widx >= 0 && widx <= 10) ? Wf[i * 11 + widx] : 0.f;
            b[j] = (short)f2b(v);
        }
        bfr[i] = b;
    }

    // QK unit assignment: u = nt*5+mt over 15 units; wave w -> u in [4w,4w+4)
    const int nu = (wv == 3) ? 3 : 4;
    int nt_t[4], mt_t[4];
    #pragma unroll
    for (int t = 0; t < 4; ++t) {
        int u = wv * 4 + t;
        if (u > 14) u = 14;
        nt_t[t] = u / 5; mt_t[t] = u - (u / 5) * 5;
    }

    floatx4 acc[8];
    #pragma unroll
    for (int nt = 0; nt < 8; ++nt) acc[nt] = (floatx4){0.f, 0.f, 0.f, 0.f};
    float m_run[4] = {-INFINITY, -INFINITY, -INFINITY, -INFINITY};
    float l_run[4] = {0.f, 0.f, 0.f, 0.f};

    const int nkt = 2 * qt + 2;
    for (int kt = 0; kt < nkt; ++kt) {
        const int k0 = kt * TK;
        const int buf = kt & 1;

        // ---- QK^T: 80x48 halo score tile via MFMA, masked, bf16 -> LDS -----
        for (int t = 0; t < nu; ++t) {
            const int nt = nt_t[t], mt = mt_t[t];
            const unsigned short* krow = Kb + (size_t)(k0 + 8 + nt * 16 + l15) * D_;
            floatx4 s = {0.f, 0.f, 0.f, 0.f};
            #pragma unroll
            for (int kc = 0; kc < 4; ++kc) {
                short8 kf = *(const short8*)(krow + kc * 32 + qd * 8);
                short8 qf = *(const short8*)&Qs[mt * 16 + l15][kc * 32 + qd * 8];
                s = __builtin_amdgcn_mfma_f32_16x16x32_bf16(qf, kf, s, 0, 0, 0);
            }
            const int qrow = q0 - 16 + mt * 16 + qd * 4;
            const int kcol = k0 - 8 + nt * 16 + l15;
            #pragma unroll
            for (int reg = 0; reg < 4; ++reg)
                sc[buf][mt * 16 + qd * 4 + reg][nt * 16 + l15] =
                    (kcol <= qrow + reg) ? f2b(s[reg]) : (unsigned short)0;
        }
        __syncthreads();   // sc[buf] ready (writes of next tile go to other buf)

        // ---- conv via banded MFMA: wave owns out rows wv*16..+15 -----------
        floatx4 cv[2];
        #pragma unroll
        for (int n = 0; n < 2; ++n) {
            floatx4 c4 = {0.f, 0.f, 0.f, 0.f};
            #pragma unroll
            for (int i = 0; i < 6; ++i) {
                short8 af = *(const short8*)&sc[buf][wv * 16 + l15 + 11 + i][n * 16 + qd * 8];
                c4 = __builtin_amdgcn_mfma_f32_16x16x32_bf16(af, bfr[i], c4, 0, 0, 0);
            }
            cv[n] = c4;
        }

        // ---- softmax in C-layout registers (rows qd*4+reg, col 16n+l15) ----
        float lg[2][4];
        #pragma unroll
        for (int n = 0; n < 2; ++n)
            #pragma unroll
            for (int reg = 0; reg < 4; ++reg) {
                const int q = q0 + wv * 16 + qd * 4 + reg;
                const int k = k0 + n * 16 + l15;
                lg[n][reg] = (k <= q) ? cv[n][reg] * SCALE : -1e30f;
            }
        float alpha[4];
        float p[2][4];
        #pragma unroll
        for (int reg = 0; reg < 4; ++reg) {
            float mx = fmaxf(lg[0][reg], lg[1][reg]);
            mx = fmaxf(mx, __shfl_xor(mx, 1));
            mx = fmaxf(mx, __shfl_xor(mx, 2));
            mx = fmaxf(mx, __shfl_xor(mx, 4));
            mx = fmaxf(mx, __shfl_xor(mx, 8));
            const float nm = fmaxf(m_run[reg], mx);
            alpha[reg] = __expf(m_run[reg] - nm);
            p[0][reg] = __expf(lg[0][reg] - nm);
            p[1][reg] = __expf(lg[1][reg] - nm);
            float sum = p[0][reg] + p[1][reg];
            sum += __shfl_xor(sum, 1);
            sum += __shfl_xor(sum, 2);
            sum += __shfl_xor(sum, 4);
            sum += __shfl_xor(sum, 8);
            l_run[reg] = l_run[reg] * alpha[reg] + sum;
            m_run[reg] = nm;
        }

        // ---- P (C-layout) -> per-wave LDS strip -> A-layout ----------------
        #pragma unroll
        for (int n = 0; n < 2; ++n)
            #pragma unroll
            for (int reg = 0; reg < 4; ++reg)
                Pst[wv][qd * 4 + reg][n * 16 + l15] = f2b(p[n][reg]);

        // rescale accumulator (alpha rows == acc rows, in-register)
        #pragma unroll
        for (int nt = 0; nt < 8; ++nt)
            #pragma unroll
            for (int reg = 0; reg < 4; ++reg)
                acc[nt][reg] *= alpha[reg];

        // ---- P @ V via MFMA: wave's 16 rows x all 128 D-cols ---------------
        {
            short8 pf = *(const short8*)&Pst[wv][l15][qd * 8];
            #pragma unroll
            for (int nt = 0; nt < 8; ++nt) {
                short8 vf = *(const short8*)(Vb + (size_t)(nt * 16 + l15) * S_ + k0 + qd * 8);
                acc[nt] = __builtin_amdgcn_mfma_f32_16x16x32_bf16(pf, vf, acc[nt], 0, 0, 0);
            }
        }
    }

    // ---- epilogue: normalize + store (C-layout rows in-register) -----------
    {
        float inv[4];
        #pragma unroll
        for (int reg = 0; reg < 4; ++reg) inv[reg] = 1.0f / l_run[reg];
        float* Ob = O + (size_t)bh * S_ * D_;
        #pragma unroll
        for (int reg = 0; reg < 4; ++reg) {
            const int row = q0 + wv * 16 + qd * 4 + reg;
            #pragma unroll
            for (int nt = 0; nt < 8; ++nt)
                Ob[(size_t)row * D_ + nt * 16 + l15] = acc[nt][reg] * inv[reg];
        }
    }
}

extern "C" void kernel_launch(void* const* d_in, const int* in_sizes, int n_in,
                              void* d_out, int out_size, void* d_ws, size_t ws_size,
                              hipStream_t stream) {
    const float* Q = (const float*)d_in[0];
    const float* K = (const float*)d_in[1];
    const float* V = (const float*)d_in[2];
    const float* W = (const float*)d_in[3];
    float* O = (float*)d_out;

    unsigned short* Qp = (unsigned short*)d_ws;                        // 6389760 B
    unsigned short* Kp = (unsigned short*)((char*)d_ws + 6389760);     // 6488064 B
    unsigned short* Vt = (unsigned short*)((char*)d_ws + 12877824);    // 6291456 B

    prep_kernel<<<dim3(QBLK + KBLK + VBLK), dim3(256), 0, stream>>>(Q, K, V, Qp, Kp, Vt);
    conv_attn_mfma<<<dim3(B_ * H_ * (S_ / TQ)), dim3(256), 0, stream>>>(Qp, Kp, Vt, W, O);
}

// Round 7
// 201.971 us; speedup vs baseline: 1.2112x; 1.2112x over previous
//
#include <hip/hip_runtime.h>
#include <hip/hip_bf16.h>
#include <math.h>

#define B_ 2
#define H_ 12
#define S_ 1024
#define D_ 128
#define TQ 32
#define TK 32
#define SCALE 0.08838834764831843f

#define KROWS (16 + S_ + 16)       /* 1056, zero-padded 16 both sides */
#define KBLK 3168                  /* 24*1056*128/4/256 */
#define VBLK 3072                  /* 24*32*4 transpose tiles */

typedef __attribute__((ext_vector_type(8))) short short8;
typedef __attribute__((ext_vector_type(4))) float floatx4;

__device__ __forceinline__ unsigned short f2b(float f) {
    return __builtin_bit_cast(unsigned short, __float2bfloat16(f));
}

// ---- prepass: K f32->bf16 padded rows; V -> V^T bf16 -----------------------
__global__ __launch_bounds__(256) void prep_kernel(
    const float* __restrict__ K, const float* __restrict__ V,
    unsigned short* __restrict__ Kp, unsigned short* __restrict__ Vt)
{
    __shared__ float ls[32][33];
    const int bid = blockIdx.x;
    const int tid = threadIdx.x;
    if (bid < KBLK) {
        int e0 = (bid * 256 + tid) * 4;
        int bh = e0 / (KROWS * D_);
        int rem = e0 - bh * (KROWS * D_);
        int r = rem >> 7, d = rem & 127;
        int sr = r - 16;
        float4 v = make_float4(0.f, 0.f, 0.f, 0.f);
        if (sr >= 0 && sr < S_) v = *(const float4*)(K + ((size_t)bh * S_ + sr) * D_ + d);
        ushort4 o; o.x = f2b(v.x); o.y = f2b(v.y); o.z = f2b(v.z); o.w = f2b(v.w);
        *(ushort4*)(Kp + ((size_t)bh * KROWS + r) * D_ + d) = o;
    } else {
        int b = bid - KBLK;
        int dt = b & 3; int kt = (b >> 2) & 31; int bh = b >> 7;
        int lk = tid >> 3, ld = (tid & 7) * 4;
        float4 v = *(const float4*)(V + ((size_t)bh * S_ + kt * 32 + lk) * D_ + dt * 32 + ld);
        ls[lk][ld + 0] = v.x; ls[lk][ld + 1] = v.y; ls[lk][ld + 2] = v.z; ls[lk][ld + 3] = v.w;
        __syncthreads();
        int lk2 = tid >> 3, lc = (tid & 7) * 4;
        ushort4 o;
        o.x = f2b(ls[lc + 0][lk2]); o.y = f2b(ls[lc + 1][lk2]);
        o.z = f2b(ls[lc + 2][lk2]); o.w = f2b(ls[lc + 3][lk2]);
        *(ushort4*)(Vt + ((size_t)bh * D_ + dt * 32 + lk2) * S_ + kt * 32 + lc) = o;
    }
}

// ---- main kernel: 4 independent waves, k-tiles mod 4, no in-loop barriers --
__global__ __launch_bounds__(256, 3) void conv_attn_mfma(
    const float* __restrict__ Q,            // [24][1024][128] f32
    const unsigned short* __restrict__ Kp,  // [24][1056][128] bf16
    const unsigned short* __restrict__ Vt,  // [24][128][1024] bf16
    const float* __restrict__ W,            // [12][6][11]
    float* __restrict__ O)                  // [24][1024][128] f32
{
    __shared__ __align__(16) unsigned short Qs[48][136];       // 13056 B
    __shared__ __align__(16) union {
        unsigned short sc[4][48][56];       // 21504 B (per-wave bf16 score strips)
        float oacc[32][132];                // 16896 B (merge buffer, post-loop)
    } u;
    __shared__ __align__(16) unsigned short Pst[4][32][40];    // 10240 B
    __shared__ float m_all[4][32], l_all[4][32], ms_s[32], inv_s[32];
    __shared__ float Wf[66];

    const int tid = threadIdx.x;
    const int wv = tid >> 6;
    const int ln = tid & 63;
    const int l15 = ln & 15;
    const int qd = ln >> 4;

    // XCD swizzle: XCD x (bid%8) sees only bh in {3x..3x+2}; heavy/light qt pairing
    const int bid = blockIdx.x;
    const int bh = (bid & 7) * 3 + ((bid >> 3) % 3);
    const int g = bid / 24;
    const int qt = (g & 1) ? (g >> 1) : (31 - (g >> 1));
    const int h = bh % H_;
    const int q0 = qt * TQ;

    if (tid < 66) Wf[tid] = W[h * 66 + tid];

    // stage Q rows q0-16 .. q0+31 (f32 -> bf16 in-kernel)
    const float* Qb = Q + (size_t)bh * S_ * D_;
    for (int idx = tid; idx < 48 * 32; idx += 256) {
        int r = idx >> 5, c4 = (idx & 31) * 4;
        int row = q0 - 16 + r;
        float4 v = make_float4(0.f, 0.f, 0.f, 0.f);
        if (row >= 0) v = *(const float4*)(Qb + (size_t)row * D_ + c4);
        ushort4 o; o.x = f2b(v.x); o.y = f2b(v.y); o.z = f2b(v.z); o.w = f2b(v.w);
        *(ushort4*)&Qs[r][c4] = o;
    }
    __syncthreads();

    // banded-Toeplitz conv B-fragments: B_i[t][c] = W[i][t-c-3]
    short8 bfr[6];
    #pragma unroll
    for (int i = 0; i < 6; ++i) {
        short8 b;
        #pragma unroll
        for (int j = 0; j < 8; ++j) {
            int widx = qd * 8 + j - l15 - 3;
            float v = (widx >= 0 && widx <= 10) ? Wf[i * 11 + widx] : 0.f;
            b[j] = (short)f2b(v);
        }
        bfr[i] = b;
    }

    const unsigned short* Kb = Kp + (size_t)bh * KROWS * D_;
    const unsigned short* Vb = Vt + (size_t)bh * D_ * S_;

    floatx4 acc[2][8];
    #pragma unroll
    for (int m2 = 0; m2 < 2; ++m2)
        #pragma unroll
        for (int nt = 0; nt < 8; ++nt)
            acc[m2][nt] = (floatx4){0.f, 0.f, 0.f, 0.f};
    float m_run[2][4], l_run[2][4];
    #pragma unroll
    for (int m2 = 0; m2 < 2; ++m2)
        #pragma unroll
        for (int reg = 0; reg < 4; ++reg) { m_run[m2][reg] = -INFINITY; l_run[m2][reg] = 0.f; }

    for (int kt = wv; kt <= qt; kt += 4) {
        const int k0 = kt * TK;

        // ---- QK^T: private 48x48 halo score tile, masked, bf16 -> sc[wv] ---
        #pragma unroll
        for (int nt = 0; nt < 3; ++nt) {
            const unsigned short* krow = Kb + (size_t)(k0 + 8 + nt * 16 + l15) * D_;
            short8 kf[4];
            #pragma unroll
            for (int kc = 0; kc < 4; ++kc)
                kf[kc] = *(const short8*)(krow + kc * 32 + qd * 8);
            #pragma unroll
            for (int mt = 0; mt < 3; ++mt) {
                floatx4 s = {0.f, 0.f, 0.f, 0.f};
                #pragma unroll
                for (int kc = 0; kc < 4; ++kc) {
                    short8 qf = *(const short8*)&Qs[mt * 16 + l15][kc * 32 + qd * 8];
                    s = __builtin_amdgcn_mfma_f32_16x16x32_bf16(qf, kf[kc], s, 0, 0, 0);
                }
                const int qrow = q0 - 16 + mt * 16 + qd * 4;
                const int kcol = k0 - 8 + nt * 16 + l15;
                #pragma unroll
                for (int reg = 0; reg < 4; ++reg)
                    u.sc[wv][mt * 16 + qd * 4 + reg][nt * 16 + l15] =
                        (kcol <= qrow + reg) ? f2b(s[reg]) : (unsigned short)0;
            }
        }

        // ---- conv via banded MFMA (same-wave LDS dep only) -----------------
        floatx4 cv[2][2];
        #pragma unroll
        for (int m2 = 0; m2 < 2; ++m2)
            #pragma unroll
            for (int n = 0; n < 2; ++n) {
                floatx4 c4 = {0.f, 0.f, 0.f, 0.f};
                #pragma unroll
                for (int i = 0; i < 6; ++i) {
                    short8 af = *(const short8*)&u.sc[wv][m2 * 16 + l15 + 11 + i][n * 16 + qd * 8];
                    c4 = __builtin_amdgcn_mfma_f32_16x16x32_bf16(af, bfr[i], c4, 0, 0, 0);
                }
                cv[m2][n] = c4;
            }

        // ---- online softmax (C-layout registers) ---------------------------
        float alpha[2][4];
        #pragma unroll
        for (int m2 = 0; m2 < 2; ++m2) {
            #pragma unroll
            for (int reg = 0; reg < 4; ++reg) {
                const int q = q0 + m2 * 16 + qd * 4 + reg;
                float lg0 = (k0 + l15 <= q)      ? cv[m2][0][reg] * SCALE : -1e30f;
                float lg1 = (k0 + 16 + l15 <= q) ? cv[m2][1][reg] * SCALE : -1e30f;
                float mx = fmaxf(lg0, lg1);
                mx = fmaxf(mx, __shfl_xor(mx, 1));
                mx = fmaxf(mx, __shfl_xor(mx, 2));
                mx = fmaxf(mx, __shfl_xor(mx, 4));
                mx = fmaxf(mx, __shfl_xor(mx, 8));
                const float nm = fmaxf(m_run[m2][reg], mx);
                alpha[m2][reg] = __expf(m_run[m2][reg] - nm);
                float p0 = __expf(lg0 - nm);
                float p1 = __expf(lg1 - nm);
                float sum = p0 + p1;
                sum += __shfl_xor(sum, 1);
                sum += __shfl_xor(sum, 2);
                sum += __shfl_xor(sum, 4);
                sum += __shfl_xor(sum, 8);
                l_run[m2][reg] = l_run[m2][reg] * alpha[m2][reg] + sum;
                m_run[m2][reg] = nm;
                Pst[wv][m2 * 16 + qd * 4 + reg][l15]      = f2b(p0);
                Pst[wv][m2 * 16 + qd * 4 + reg][16 + l15] = f2b(p1);
            }
        }

        // rescale accumulator (alpha rows == acc rows, in-register)
        #pragma unroll
        for (int m2 = 0; m2 < 2; ++m2)
            #pragma unroll
            for (int reg = 0; reg < 4; ++reg) {
                const float a = alpha[m2][reg];
                #pragma unroll
                for (int nt = 0; nt < 8; ++nt)
                    acc[m2][nt][reg] *= a;
            }

        // ---- P @ V via MFMA -------------------------------------------------
        {
            short8 pf[2];
            #pragma unroll
            for (int m2 = 0; m2 < 2; ++m2)
                pf[m2] = *(const short8*)&Pst[wv][m2 * 16 + l15][qd * 8];
            #pragma unroll
            for (int nt = 0; nt < 8; ++nt) {
                short8 vf = *(const short8*)(Vb + (size_t)(nt * 16 + l15) * S_ + k0 + qd * 8);
                #pragma unroll
                for (int m2 = 0; m2 < 2; ++m2)
                    acc[m2][nt] = __builtin_amdgcn_mfma_f32_16x16x32_bf16(pf[m2], vf, acc[m2][nt], 0, 0, 0);
            }
        }
    }

    // ---- merge the 4 waves' partials ---------------------------------------
    if (l15 == 0) {
        #pragma unroll
        for (int m2 = 0; m2 < 2; ++m2)
            #pragma unroll
            for (int reg = 0; reg < 4; ++reg) {
                const int r = m2 * 16 + qd * 4 + reg;
                m_all[wv][r] = m_run[m2][reg];
                l_all[wv][r] = l_run[m2][reg];
            }
    }
    __syncthreads();
    if (tid < 32) {
        float ms = -INFINITY;
        #pragma unroll
        for (int w = 0; w < 4; ++w) ms = fmaxf(ms, m_all[w][tid]);
        float ls = 0.f;
        #pragma unroll
        for (int w = 0; w < 4; ++w) ls += __expf(m_all[w][tid] - ms) * l_all[w][tid];
        ms_s[tid] = ms;
        inv_s[tid] = 1.f / ls;
    }
    __syncthreads();
    for (int w = 0; w < 4; ++w) {
        if (wv == w) {
            #pragma unroll
            for (int m2 = 0; m2 < 2; ++m2)
                #pragma unroll
                for (int reg = 0; reg < 4; ++reg) {
                    const int r = m2 * 16 + qd * 4 + reg;
                    const float f = __expf(m_run[m2][reg] - ms_s[r]);
                    #pragma unroll
                    for (int nt = 0; nt < 8; ++nt) {
                        const float val = acc[m2][nt][reg] * f;
                        if (w == 0) u.oacc[r][nt * 16 + l15] = val;
                        else        u.oacc[r][nt * 16 + l15] += val;
                    }
                }
        }
        __syncthreads();
    }

    // ---- normalize + store --------------------------------------------------
    {
        const int r = tid >> 3;
        const int c0 = (tid & 7) * 16;
        const float inv = inv_s[r];
        float* orow = O + ((size_t)bh * S_ + q0 + r) * D_ + c0;
        #pragma unroll
        for (int g4 = 0; g4 < 4; ++g4) {
            float4 o;
            o.x = u.oacc[r][c0 + g4 * 4 + 0] * inv;
            o.y = u.oacc[r][c0 + g4 * 4 + 1] * inv;
            o.z = u.oacc[r][c0 + g4 * 4 + 2] * inv;
            o.w = u.oacc[r][c0 + g4 * 4 + 3] * inv;
            *(float4*)(orow + g4 * 4) = o;
        }
    }
}

extern "C" void kernel_launch(void* const* d_in, const int* in_sizes, int n_in,
                              void* d_out, int out_size, void* d_ws, size_t ws_size,
                              hipStream_t stream) {
    const float* Q = (const float*)d_in[0];
    const float* K = (const float*)d_in[1];
    const float* V = (const float*)d_in[2];
    const float* W = (const float*)d_in[3];
    float* O = (float*)d_out;

    unsigned short* Kp = (unsigned short*)d_ws;                        // 6488064 B
    unsigned short* Vt = (unsigned short*)((char*)d_ws + 6488064);     // 6291456 B

    prep_kernel<<<dim3(KBLK + VBLK), dim3(256), 0, stream>>>(K, V, Kp, Vt);
    conv_attn_mfma<<<dim3(B_ * H_ * (S_ / TQ)), dim3(256), 0, stream>>>(Q, Kp, Vt, W, O);
}